// Round 4
// baseline (83.516 us; speedup 1.0000x reference)
//
#include <hip/hip_runtime.h>
#include <math.h>

#define BATCH  8192
#define KNEI   30
#define LATENT 256
#define NDIST  60
#define CHUNK  10
#define NCHUNK (NDIST / CHUNK)

// One wave (64 lanes) per batch element; 4 batch elements per 256-thread block.
// No LDS, no barriers: softmax runs on per-lane distance registers.
__global__ __launch_bounds__(256) void softnp_dist_kernel(
    const float* __restrict__ z_all,
    const int* __restrict__ knn,       // (N, K) int32
    const int* __restrict__ cell,      // (B,)
    const int* __restrict__ neg,       // (B, K)
    float* __restrict__ losses)        // (B,)
{
    const int tid  = threadIdx.x;
    const int wave = tid >> 6;
    const int lane = tid & 63;
    const int b    = blockIdx.x * 4 + wave;

    const int ci = cell[b];

    // This lane's float4 slice of z_i (row read once per wave, L1/L2 broadcast)
    const float4 zv = reinterpret_cast<const float4*>(z_all + (size_t)ci * LATENT)[lane];

    // One coalesced index epoch: lanes 0..29 -> knn row, lanes 32..61 -> neg row.
    int myidx = 0;
    if (lane < KNEI)
        myidx = knn[(size_t)ci * KNEI + lane];
    else if (lane >= 32 && lane < 32 + KNEI)
        myidx = neg[(size_t)b * KNEI + (lane - 32)];

    // dreg will hold -dist for this lane's candidate k (lane 0..29 = knn k,
    // lane 32..61 = neg k-30); -inf elsewhere -> exp() = 0 automatically.
    float dreg = -INFINITY;

    #pragma unroll
    for (int c = 0; c < NCHUNK; ++c) {
        // ---- issue CHUNK row gathers (1 KB coalesced each) ----
        float4 v[CHUNK];
        #pragma unroll
        for (int j = 0; j < CHUNK; ++j) {
            const int k   = c * CHUNK + j;
            const int src = (k < KNEI) ? k : k + 2;          // skip lanes 30,31
            const int idx = __shfl(myidx, src, 64);          // wave-uniform
            v[j] = reinterpret_cast<const float4*>(z_all + (size_t)idx * LATENT)[lane];
        }

        // ---- per-lane partial squared distances ----
        float s[CHUNK];
        #pragma unroll
        for (int j = 0; j < CHUNK; ++j) {
            const float dx = v[j].x - zv.x;
            const float dy = v[j].y - zv.y;
            const float dz = v[j].z - zv.z;
            const float dw = v[j].w - zv.w;
            s[j] = dx * dx + dy * dy + dz * dz + dw * dw;
        }

        // ---- batched xor-butterfly: after this every lane holds each sum ----
        #pragma unroll
        for (int off = 32; off > 0; off >>= 1) {
            #pragma unroll
            for (int j = 0; j < CHUNK; ++j)
                s[j] += __shfl_xor(s[j], off, 64);
        }

        // ---- deposit -dist into the owning lane's register ----
        #pragma unroll
        for (int j = 0; j < CHUNK; ++j) {
            const int k   = c * CHUNK + j;
            const int src = (k < KNEI) ? k : k + 2;
            if (lane == src) dreg = -sqrtf(s[j]);
        }
    }

    // ---- in-wave softmax over -dist (TEMPERATURE == 1) ----
    float m = dreg;
    #pragma unroll
    for (int off = 32; off > 0; off >>= 1)
        m = fmaxf(m, __shfl_xor(m, off, 64));

    const float e   = expf(dreg - m);                 // -inf lanes -> 0
    float tot = e;
    float top = (lane < KNEI) ? e : 0.0f;
    #pragma unroll
    for (int off = 32; off > 0; off >>= 1) {
        tot += __shfl_xor(tot, off, 64);
        top += __shfl_xor(top, off, 64);
    }

    if (lane == 0)
        losses[b] = -logf(top / tot + 1e-8f);
}

// Deterministic mean over the 8192 per-element losses.
__global__ __launch_bounds__(1024) void softnp_reduce_kernel(
    const float* __restrict__ losses, float* __restrict__ out)
{
    const int tid  = threadIdx.x;
    const int wave = tid >> 6;
    const int lane = tid & 63;

    float s = 0.0f;
    for (int i = tid; i < BATCH; i += 1024)
        s += losses[i];

    #pragma unroll
    for (int off = 32; off > 0; off >>= 1)
        s += __shfl_xor(s, off, 64);

    __shared__ float buf[16];
    if (lane == 0) buf[wave] = s;
    __syncthreads();

    if (tid == 0) {
        float t = 0.0f;
        #pragma unroll
        for (int i = 0; i < 16; ++i) t += buf[i];
        out[0] = t / (float)BATCH;
    }
}

extern "C" void kernel_launch(void* const* d_in, const int* in_sizes, int n_in,
                              void* d_out, int out_size, void* d_ws, size_t ws_size,
                              hipStream_t stream) {
    const float* z_all = (const float*)d_in[0];
    const int*   knn   = (const int*)d_in[1];
    const int*   cell  = (const int*)d_in[2];
    const int*   neg   = (const int*)d_in[3];
    float* out    = (float*)d_out;
    float* losses = (float*)d_ws;   // BATCH floats of scratch

    softnp_dist_kernel<<<BATCH / 4, 256, 0, stream>>>(z_all, knn, cell, neg, losses);
    softnp_reduce_kernel<<<1, 1024, 0, stream>>>(losses, out);
}